// Round 6
// baseline (261.739 us; speedup 1.0000x reference)
//
#include <hip/hip_runtime.h>
#include <stdint.h>

#define BATCH 64
#define HH 512
#define NR 256
#define BANDH 8
#define NBANDS (256 / BANDH)   // 32 bands over dy' in [0,256)

// LDS aperture: low 32 bits of a generic pointer to __shared__ = LDS offset.
__device__ __forceinline__ uint32_t lds_off(const void* p) {
    return (uint32_t)(uintptr_t)p;
}

// Native fire-and-forget LDS fp32 atomics into 4 comp-major tables of 257
// floats (strides 1028 B). Ordering vs the merge phase is enforced by the
// explicit waitcnt asm + __syncthreads. (Proven in rounds 0-3.)
__device__ __forceinline__ void lds_add4(uint32_t addr, float v0, float v1,
                                         float v2, float v3) {
    asm volatile(
        "ds_add_f32 %0, %1\n\t"
        "ds_add_f32 %0, %2 offset:1028\n\t"
        "ds_add_f32 %0, %3 offset:2056\n\t"
        "ds_add_f32 %0, %4 offset:3084"
        :: "v"(addr), "v"(v0), "v"(v1), "v"(v2), "v"(v3));
}

// Two named register sets for 1-deep row pipelining (rule 20: macro-expanded
// names only, no runtime indexing). Loads are PLAIN C: the compiler tracks
// them and emits the counted vmcnt itself — set k's first use has 16 newer
// loads outstanding => vmcnt(16)-class wait, never a full drain in-loop.
#define DECL_SET(S) \
    float A1##S, B1##S, A2##S, B2##S, C1##S, D1##S, C2##S, D2##S, \
          E1##S, G1##S, E2##S, G2##S, P1##S, Q1##S, P2##S, Q2##S;

#define LOADROW(S, DY) do { \
    const size_t rp_ = ib + (size_t)(256 + (DY)) * HH; \
    const size_t rm_ = ib + (size_t)(256 - (DY)) * HH; \
    A1##S = f1r[rp_ + xp]; B1##S = f1i[rp_ + xp]; \
    A2##S = f2r[rp_ + xp]; B2##S = f2i[rp_ + xp]; \
    C1##S = f1r[rp_ + xm]; D1##S = f1i[rp_ + xm]; \
    C2##S = f2r[rp_ + xm]; D2##S = f2i[rp_ + xm]; \
    E1##S = f1r[rm_ + xp]; G1##S = f1i[rm_ + xp]; \
    E2##S = f2r[rm_ + xp]; G2##S = f2i[rm_ + xp]; \
    P1##S = f1r[rm_ + xm]; Q1##S = f1i[rm_ + xm]; \
    P2##S = f2r[rm_ + xm]; Q2##S = f2i[rm_ + xm]; \
} while (0)

#define COMPUTE(S, DY) do { \
    const int r2_ = dx2 + (DY) * (DY); \
    int bin_ = (int)sqrtf((float)r2_); \
    bin_ -= (bin_ * bin_ > r2_); \
    bin_ += ((bin_ + 1) * (bin_ + 1) <= r2_); \
    if (bin_ > 256) bin_ = 256; \
    const float my_ = ((DY) == 0) ? 0.f : 1.f; \
    float scr = A1##S * A2##S + B1##S * B2##S; \
    float sci = B1##S * A2##S - A1##S * B2##S; \
    float sp1 = A1##S * A1##S + B1##S * B1##S; \
    float sp2 = A2##S * A2##S + B2##S * B2##S; \
    scr += mx * (C1##S * C2##S + D1##S * D2##S); \
    sci += mx * (D1##S * C2##S - C1##S * D2##S); \
    sp1 += mx * (C1##S * C1##S + D1##S * D1##S); \
    sp2 += mx * (C2##S * C2##S + D2##S * D2##S); \
    scr += my_ * (E1##S * E2##S + G1##S * G2##S); \
    sci += my_ * (G1##S * E2##S - E1##S * G2##S); \
    sp1 += my_ * (E1##S * E1##S + G1##S * G1##S); \
    sp2 += my_ * (E2##S * E2##S + G2##S * G2##S); \
    const float mxy_ = mx * my_; \
    scr += mxy_ * (P1##S * P2##S + Q1##S * Q2##S); \
    sci += mxy_ * (Q1##S * P2##S - P1##S * Q2##S); \
    sp1 += mxy_ * (P1##S * P1##S + Q1##S * Q1##S); \
    sp2 += mxy_ * (P2##S * P2##S + Q2##S * Q2##S); \
    if (bin_ != cur) { \
        if (cur >= 0) \
            lds_add4(sbase + 4u * (uint32_t)cur, acr, aci, ap1, ap2); \
        acr = 0.f; aci = 0.f; ap1 = 0.f; ap2 = 0.f; \
        cur = bin_; \
    } \
    acr += scr; aci += sci; ap1 += sp1; ap2 += sp2; \
} while (0)

// 4-fold mirror + column-run-length scatter, 1-deep row-pipelined in pure C:
// source order ISSUE(k+1) -> sched_barrier(0) -> COMPUTE(k) is pinned, so
// row k+1's 16 loads are in flight while row k computes; the compiler's own
// waitcnt insertion yields the counted (never-drain) wait.
__global__ __launch_bounds__(256) void frc_fold(
    const float* __restrict__ f1r, const float* __restrict__ f1i,
    const float* __restrict__ f2r, const float* __restrict__ f2i,
    float* __restrict__ gpart /* [NBANDS][BATCH][4][NR] */)
{
    __shared__ float s_acc[4 * 257];   // [comp][bin], bin 256 = overflow
    for (int i = threadIdx.x; i < 4 * 257; i += 256) s_acc[i] = 0.f;
    __syncthreads();

    const int b    = blockIdx.y;
    const int band = blockIdx.x;
    const int w    = threadIdx.x >> 6;
    const int lane = threadIdx.x & 63;
    const int dx   = w * 64 + lane;          // 0..255
    const int dx2  = dx * dx;
    const int wmin2 = (w * 64) * (w * 64);   // min dx^2 in this wave
    const float mx = (dx == 0) ? 0.f : 1.f;  // dx=0 is its own x-mirror

    const int dy0 = band * BANDH;
    const size_t ib = (size_t)b * HH * HH;
    const int xp = 256 + dx;   // col 256..511
    const int xm = 256 - dx;   // col 1..256

    const uint32_t sbase = lds_off(s_acc);

    float acr = 0.f, aci = 0.f, ap1 = 0.f, ap2 = 0.f;
    int cur = -1;

    DECL_SET(0)
    DECL_SET(1)

    // Prologue: row dy0 into set 0. Rows 256±dy are always in-bounds
    // (dy' <= 255) so prefetching overflow-bin rows is memory-safe; compute
    // for them is skipped by the wave-uniform predicate below.
    LOADROW(0, dy0);

    #pragma unroll
    for (int k = 0; k < BANDH; ++k) {
        const int dy = dy0 + k;
        if (k + 1 < BANDH) {
            if (k & 1) LOADROW(0, dy + 1); else LOADROW(1, dy + 1);
        }
        __builtin_amdgcn_sched_barrier(0);   // pin: loads k+1 before compute k

        if (wmin2 + dy * dy < 65536) {       // wave-uniform: skip dead rows
            if (k & 1) COMPUTE(1, dy); else COMPUTE(0, dy);
        }
        __builtin_amdgcn_sched_barrier(0);   // pin: compute k before loads k+2
    }
    if (cur >= 0)
        lds_add4(sbase + 4u * (uint32_t)cur, acr, aci, ap1, ap2);

    // Drain the asm DS ops the compiler can't see, then merge.
    asm volatile("s_waitcnt lgkmcnt(0)" ::: "memory");
    __syncthreads();

    {
        // Plain coalesced stores into this block's private slice (round-2
        // atomic-free merge, proven neutral).
        const int r = threadIdx.x;  // 256 threads -> bins 0..255 (drop 256)
        float* g = gpart + ((size_t)(band * BATCH + b) * 4) * NR + r;
        g[0 * NR] = s_acc[0 * 257 + r];
        g[1 * NR] = s_acc[1 * 257 + r];
        g[2 * NR] = s_acc[2 * 257 + r];
        g[3 * NR] = s_acc[3 * 257 + r];
    }
}

__global__ __launch_bounds__(NR) void frc_finalize(
    const float* __restrict__ gpart, float* __restrict__ out)
{
    const int b = blockIdx.x;
    const int r = threadIdx.x;
    float cr = 0.f, ci = 0.f, p1 = 0.f, p2 = 0.f;
    for (int band = 0; band < NBANDS; ++band) {
        const float* g = gpart + ((size_t)(band * BATCH + b) * 4) * NR + r;
        cr += g[0 * NR];
        ci += g[1 * NR];
        p1 += g[2 * NR];
        p2 += g[3 * NR];
    }
    const float num = sqrtf(cr * cr + ci * ci);
    const float den = sqrtf(p1 * p2);
    out[(size_t)b * NR + r] = (den == 0.f) ? 0.f : num / den;
}

extern "C" void kernel_launch(void* const* d_in, const int* in_sizes, int n_in,
                              void* d_out, int out_size, void* d_ws, size_t ws_size,
                              hipStream_t stream) {
    const float* f1r = (const float*)d_in[0];
    const float* f1i = (const float*)d_in[1];
    const float* f2r = (const float*)d_in[2];
    const float* f2i = (const float*)d_in[3];
    float* out   = (float*)d_out;
    float* gpart = (float*)d_ws;   // NBANDS*BATCH*4*NR floats = 8 MiB

    (void)in_sizes; (void)n_in; (void)out_size; (void)ws_size;

    dim3 grid(NBANDS, BATCH);   // 32 x 64 = 2048 blocks, 8/CU
    frc_fold<<<grid, 256, 0, stream>>>(f1r, f1i, f2r, f2i, gpart);
    frc_finalize<<<dim3(BATCH), dim3(NR), 0, stream>>>(gpart, out);
}

// Round 8
// 246.849 us; speedup vs baseline: 1.0603x; 1.0603x over previous
//
#include <hip/hip_runtime.h>
#include <stdint.h>

#define BATCH 64
#define HH 512
#define NR 256
#define BANDH 16
#define NBANDS (256 / BANDH)   // 16 bands over dy' in [0,256)

// LDS aperture: low 32 bits of a generic pointer to __shared__ = LDS offset.
__device__ __forceinline__ uint32_t lds_off(const void* p) {
    return (uint32_t)(uintptr_t)p;
}

// Native fire-and-forget LDS fp32 atomics into 4 comp-major tables of 257
// floats (strides 1028 B). Comp-major => flushing lanes hold mostly-distinct
// consecutive bins at 4-B stride -> good bank spread. Ordering vs the merge
// phase is enforced by the explicit waitcnt asm + __syncthreads.
__device__ __forceinline__ void lds_add4(uint32_t addr, float v0, float v1,
                                         float v2, float v3) {
    asm volatile(
        "ds_add_f32 %0, %1\n\t"
        "ds_add_f32 %0, %2 offset:1028\n\t"
        "ds_add_f32 %0, %3 offset:2056\n\t"
        "ds_add_f32 %0, %4 offset:3084"
        :: "v"(addr), "v"(v0), "v"(v1), "v"(v2), "v"(v3));
}

// 4-fold mirror + column-run-length scatter — byte-identical to the round-2
// kernel except BANDH 8->16: 1024 blocks instead of 2048, same total work.
// Single-variable test of the ~55 ns/block serialization implied by rounds
// 0-6 (duration tracks block count and nothing else: all pipes <15% busy,
// warm-cache replays run identical time, per-wave MLP changes all null).
__global__ __launch_bounds__(256) void frc_fold(
    const float* __restrict__ f1r, const float* __restrict__ f1i,
    const float* __restrict__ f2r, const float* __restrict__ f2i,
    float* __restrict__ gpart /* [NBANDS][BATCH][4][NR] */)
{
    __shared__ float s_acc[4 * 257];   // [comp][bin], bin 256 = overflow
    for (int i = threadIdx.x; i < 4 * 257; i += 256) s_acc[i] = 0.f;
    __syncthreads();

    const int b    = blockIdx.y;
    const int band = blockIdx.x;
    const int w    = threadIdx.x >> 6;
    const int lane = threadIdx.x & 63;
    const int dx   = w * 64 + lane;          // 0..255
    const int dx2  = dx * dx;
    const int wmin2 = (w * 64) * (w * 64);   // min dx^2 in this wave
    const float mx = (dx == 0) ? 0.f : 1.f;  // dx=0 is its own x-mirror

    const int dy0 = band * BANDH;
    const size_t ib = (size_t)b * HH * HH;
    const uint32_t sbase = lds_off(s_acc);

    float acr = 0.f, aci = 0.f, ap1 = 0.f, ap2 = 0.f;
    int cur = -1;

    for (int dy = dy0; dy < dy0 + BANDH; ++dy) {
        if (wmin2 + dy * dy >= 65536) break;  // whole wave in overflow bins

        const int r2 = dx2 + dy * dy;         // < 2^18, exact in fp32
        int bin = (int)sqrtf((float)r2);
        bin -= (bin * bin > r2);
        bin += ((bin + 1) * (bin + 1) <= r2);
        if (bin > 256) bin = 256;

        const float my = (dy == 0) ? 0.f : 1.f;  // dy=0 is its own y-mirror

        const size_t rp = ib + (size_t)(256 + dy) * HH;
        const size_t rm = ib + (size_t)(256 - dy) * HH;
        const int xp = 256 + dx;   // 256..511
        const int xm = 256 - dx;   // 1..256

        const float A1 = f1r[rp + xp], B1 = f1i[rp + xp];
        const float A2 = f2r[rp + xp], B2 = f2i[rp + xp];
        const float C1 = f1r[rp + xm], D1 = f1i[rp + xm];
        const float C2 = f2r[rp + xm], D2 = f2i[rp + xm];
        const float E1 = f1r[rm + xp], G1 = f1i[rm + xp];
        const float E2 = f2r[rm + xp], G2 = f2i[rm + xp];
        const float P1 = f1r[rm + xm], Q1 = f1i[rm + xm];
        const float P2 = f2r[rm + xm], Q2 = f2i[rm + xm];

        // folded products over up to 4 mirror pixels
        float scr = A1 * A2 + B1 * B2;
        float sci = B1 * A2 - A1 * B2;
        float sp1 = A1 * A1 + B1 * B1;
        float sp2 = A2 * A2 + B2 * B2;

        scr += mx * (C1 * C2 + D1 * D2);
        sci += mx * (D1 * C2 - C1 * D2);
        sp1 += mx * (C1 * C1 + D1 * D1);
        sp2 += mx * (C2 * C2 + D2 * D2);

        scr += my * (E1 * E2 + G1 * G2);
        sci += my * (G1 * E2 - E1 * G2);
        sp1 += my * (E1 * E1 + G1 * G1);
        sp2 += my * (E2 * E2 + G2 * G2);

        const float mxy = mx * my;
        scr += mxy * (P1 * P2 + Q1 * Q2);
        sci += mxy * (Q1 * P2 - P1 * Q2);
        sp1 += mxy * (P1 * P1 + Q1 * Q1);
        sp2 += mxy * (P2 * P2 + Q2 * Q2);

        if (bin != cur) {
            if (cur >= 0)
                lds_add4(sbase + 4u * (uint32_t)cur, acr, aci, ap1, ap2);
            acr = 0.f; aci = 0.f; ap1 = 0.f; ap2 = 0.f;
            cur = bin;
        }
        acr += scr; aci += sci; ap1 += sp1; ap2 += sp2;
    }
    if (cur >= 0)
        lds_add4(sbase + 4u * (uint32_t)cur, acr, aci, ap1, ap2);

    // Drain the asm DS ops the compiler can't see, then merge.
    asm volatile("s_waitcnt lgkmcnt(0)" ::: "memory");
    __syncthreads();

    {
        // Plain coalesced stores into this block's private slice (round-2
        // atomic-free merge, proven neutral). Blocks that did no work still
        // write their zeroed table — no memset needed.
        const int r = threadIdx.x;  // 256 threads -> bins 0..255 (drop 256)
        float* g = gpart + ((size_t)(band * BATCH + b) * 4) * NR + r;
        g[0 * NR] = s_acc[0 * 257 + r];
        g[1 * NR] = s_acc[1 * 257 + r];
        g[2 * NR] = s_acc[2 * 257 + r];
        g[3 * NR] = s_acc[3 * 257 + r];
    }
}

__global__ __launch_bounds__(NR) void frc_finalize(
    const float* __restrict__ gpart, float* __restrict__ out)
{
    const int b = blockIdx.x;
    const int r = threadIdx.x;
    float cr = 0.f, ci = 0.f, p1 = 0.f, p2 = 0.f;
    for (int band = 0; band < NBANDS; ++band) {
        const float* g = gpart + ((size_t)(band * BATCH + b) * 4) * NR + r;
        cr += g[0 * NR];
        ci += g[1 * NR];
        p1 += g[2 * NR];
        p2 += g[3 * NR];
    }
    const float num = sqrtf(cr * cr + ci * ci);
    const float den = sqrtf(p1 * p2);
    out[(size_t)b * NR + r] = (den == 0.f) ? 0.f : num / den;
}

extern "C" void kernel_launch(void* const* d_in, const int* in_sizes, int n_in,
                              void* d_out, int out_size, void* d_ws, size_t ws_size,
                              hipStream_t stream) {
    const float* f1r = (const float*)d_in[0];
    const float* f1i = (const float*)d_in[1];
    const float* f2r = (const float*)d_in[2];
    const float* f2i = (const float*)d_in[3];
    float* out   = (float*)d_out;
    float* gpart = (float*)d_ws;   // NBANDS*BATCH*4*NR floats = 4 MiB

    (void)in_sizes; (void)n_in; (void)out_size; (void)ws_size;

    dim3 grid(NBANDS, BATCH);   // 16 x 64 = 1024 blocks, 4/CU
    frc_fold<<<grid, 256, 0, stream>>>(f1r, f1i, f2r, f2i, gpart);
    frc_finalize<<<dim3(BATCH), dim3(NR), 0, stream>>>(gpart, out);
}